// Round 15
// baseline (68.947 us; speedup 1.0000x reference)
//
#include <hip/hip_runtime.h>
#include <stdint.h>

#define T_LEN 2048

typedef unsigned short ushort_t;
typedef short bf16x8 __attribute__((ext_vector_type(8)));
typedef float f32x4  __attribute__((ext_vector_type(4)));

__device__ __forceinline__ unsigned short f2bf(float f) {
  union { float f; unsigned int u; } v; v.f = f;
  unsigned int u = v.u;
  return (unsigned short)((u + 0x7FFFu + ((u >> 16) & 1u)) >> 16);
}
__device__ __forceinline__ bf16x8 cvt8v(float4 a, float4 b) {
  bf16x8 r;
  r[0] = (short)f2bf(a.x); r[1] = (short)f2bf(a.y);
  r[2] = (short)f2bf(a.z); r[3] = (short)f2bf(a.w);
  r[4] = (short)f2bf(b.x); r[5] = (short)f2bf(b.y);
  r[6] = (short)f2bf(b.z); r[7] = (short)f2bf(b.w);
  return r;
}

// Panel-major XCD swizzle: all bx-blocks of one by-row land on one XCD.
__device__ __forceinline__ void xcd_swizzle_panel(int& bx, int& by) {
  int s = blockIdx.y * gridDim.x + blockIdx.x;
  int xcd = s & 7, idx = s >> 3;
  by = xcd + 8 * (idx / gridDim.x);
  bx = idx % gridDim.x;
}

// ---------------- convert fp32 -> bf16 (weights only) ----------------
__global__ __launch_bounds__(256) void cvt_w(
    const float4* __restrict__ w1, const float4* __restrict__ w2,
    ushort4* __restrict__ w1b, ushort4* __restrict__ w2b) {
  const int NW14 = (1536 * 512) / 4;
  const int NW24 = (512 * 512) / 4;
  int i = blockIdx.x * 256 + threadIdx.x;
  float4 v; ushort4* dst;
  if (i < NW14) { v = w1[i]; dst = w1b + i; }
  else { int j = i - NW14; if (j >= NW24) return; v = w2[j]; dst = w2b + j; }
  ushort4 o; o.x = f2bf(v.x); o.y = f2bf(v.y); o.z = f2bf(v.z); o.w = f2bf(v.w);
  *dst = o;
}

// ---- gemm1 (fused x-cvt, T14 issue-early/write-late, 1 barrier/iter) ----
// C_bf16 = x_f32[M][K] @ W_bf16[N][K]^T + bias. 128x192 tile, BK=64, 512 thr.
// A: f32 loads issued at iter top, cvt+swizzled ds_write AFTER MFMA (latency
//    hidden under ds_read+MFMA). B: global_load_lds. All writes to buf[cur^1]
//    drained (vmcnt0+lgkm0) before the single end-of-iter barrier.
__global__ __launch_bounds__(512, 4) void gemm1_fused(
    const float* __restrict__ Af, const ushort_t* __restrict__ Bm,
    const float* __restrict__ bias, ushort_t* __restrict__ Cb, int N, int K) {
  int bx, by; xcd_swizzle_panel(bx, by);
  const int bm = by * 128, bn = bx * 192;
  __shared__ __align__(16) ushort_t As[2][128 * 64];
  __shared__ __align__(16) ushort_t Bs[2][192 * 64];
  const int tid = threadIdx.x;
  const int lane = tid & 63, wave = tid >> 6;
  const int wr = wave & 1, wc = wave >> 1;
  const int l15 = lane & 15, lg = lane >> 4;
  const int sr8 = lane >> 3;
  const int skb = ((lane & 7) ^ sr8) << 4;      // B source swizzle
  const int sxor = (l15 & 7) << 4;              // read-side XOR
  const int arow = tid >> 2, aseg = tid & 3, ar7 = arow & 7;
  const int au0 = ((aseg * 2) ^ ar7) << 4, au1 = ((aseg * 2 + 1) ^ ar7) << 4;
  const float* asrc = Af + (size_t)(bm + arow) * K + aseg * 16;
  f32x4 acc[4][3] = {};

#define STAGE_B(buf, kt_)                                          \
  _Pragma("unroll")                                                \
  for (int c = 0; c < 3; ++c) {                                    \
    int chunk = wave * 3 + c;                                      \
    int row = chunk * 8 + sr8;                                     \
    __builtin_amdgcn_global_load_lds(                              \
        (const __attribute__((address_space(1))) unsigned int*)    \
            ((const char*)(Bm + (size_t)(bn + row) * K + (kt_)) + skb), \
        (__attribute__((address_space(3))) unsigned int*)((buf) + chunk * 512), \
        16, 0, 0);                                                 \
  }

  // prologue: stage tile 0, full drain, barrier
  {
    const float4* ap = (const float4*)asrc;
    float4 p0 = ap[0], p1 = ap[1], p2 = ap[2], p3 = ap[3];
    STAGE_B(Bs[0], 0);
    char* dst = (char*)As[0] + arow * 128;
    *(bf16x8*)(dst + au0) = cvt8v(p0, p1);
    *(bf16x8*)(dst + au1) = cvt8v(p2, p3);
    asm volatile("s_waitcnt vmcnt(0) lgkmcnt(0)" ::: "memory");
    __builtin_amdgcn_s_barrier();
  }

  const int NT = K >> 6;
  for (int t = 0; t < NT; ++t) {
    const int cur = t & 1;
    float4 p0, p1, p2, p3;
    if (t + 1 < NT) {
      const float4* ap = (const float4*)(asrc + ((t + 1) << 6));
      p0 = ap[0]; p1 = ap[1]; p2 = ap[2]; p3 = ap[3];   // issue-early
      STAGE_B(Bs[cur ^ 1], (t + 1) << 6);                // 3 gload_lds fly
    }

    bf16x8 af[2][4], bfr[2][3];
#pragma unroll
    for (int kg = 0; kg < 2; ++kg) {
#pragma unroll
      for (int m = 0; m < 4; ++m) {
        int ra = wr * 64 + m * 16 + l15;
        af[kg][m] = *(const bf16x8*)((const char*)As[cur] + ra * 128 +
                                     ((kg * 64 + lg * 16) ^ sxor));
      }
#pragma unroll
      for (int n = 0; n < 3; ++n) {
        int rb = wc * 48 + n * 16 + l15;
        bfr[kg][n] = *(const bf16x8*)((const char*)Bs[cur] + rb * 128 +
                                      ((kg * 64 + lg * 16) ^ sxor));
      }
    }

    __builtin_amdgcn_s_setprio(1);
#pragma unroll
    for (int kg = 0; kg < 2; ++kg)
#pragma unroll
      for (int m = 0; m < 4; ++m)
#pragma unroll
        for (int n = 0; n < 3; ++n)
          acc[m][n] = __builtin_amdgcn_mfma_f32_16x16x32_bf16(
              af[kg][m], bfr[kg][n], acc[m][n], 0, 0, 0);
    __builtin_amdgcn_s_setprio(0);
    __builtin_amdgcn_sched_barrier(0);   // keep cvt/ds_write AFTER the MFMAs

    if (t + 1 < NT) {
      // write-late: A loads have had ds_read+MFMA (~500cy) to land
      char* dst = (char*)As[cur ^ 1] + arow * 128;
      *(bf16x8*)(dst + au0) = cvt8v(p0, p1);
      *(bf16x8*)(dst + au1) = cvt8v(p2, p3);
      asm volatile("s_waitcnt vmcnt(0) lgkmcnt(0)" ::: "memory");
    }
    __builtin_amdgcn_s_barrier();
  }
#undef STAGE_B

  // C/D layout: col = lane&15, row = (lane>>4)*4 + j
#pragma unroll
  for (int m = 0; m < 4; ++m)
#pragma unroll
    for (int n = 0; n < 3; ++n) {
      int row0 = bm + wr * 64 + m * 16 + lg * 4;
      int col = bn + wc * 48 + n * 16 + l15;
      float bb = bias[col];
#pragma unroll
      for (int j = 0; j < 4; ++j)
        Cb[(size_t)(row0 + j) * N + col] = f2bf(acc[m][n][j] + bb);
    }
}

// ---- stage 128x64 A-tile + 64x64 B-tile, 8 waves (round-13, gemm2) ----
__device__ __forceinline__ void stage_tile64(
    const ushort_t* __restrict__ A, const ushort_t* __restrict__ Bm,
    ushort_t* As, ushort_t* Bs, int bm, int bn, int K, int kt,
    int wave, int sr8, int skb) {
#pragma unroll
  for (int c = 0; c < 2; ++c) {
    int chunk = wave * 2 + c;
    int row = chunk * 8 + sr8;
    __builtin_amdgcn_global_load_lds(
        (const __attribute__((address_space(1))) unsigned int*)
            ((const char*)(A + (size_t)(bm + row) * K + kt) + skb),
        (__attribute__((address_space(3))) unsigned int*)(As + chunk * 512),
        16, 0, 0);
  }
  {
    int row = wave * 8 + sr8;
    __builtin_amdgcn_global_load_lds(
        (const __attribute__((address_space(1))) unsigned int*)
            ((const char*)(Bm + (size_t)(bn + row) * K + kt) + skb),
        (__attribute__((address_space(3))) unsigned int*)(Bs + wave * 512),
        16, 0, 0);
  }
}

// ---- gemm2: 128x64 tile (round-13 proven, unchanged) ----
__global__ __launch_bounds__(512, 4) void gemm_db64(
    const ushort_t* __restrict__ A, const ushort_t* __restrict__ Bm,
    const float* __restrict__ bias, float* __restrict__ Cf, int N, int K) {
  int bx, by; xcd_swizzle_panel(bx, by);
  const int bm = by * 128, bn = bx * 64;
  __shared__ __align__(16) ushort_t As[2][128 * 64];
  __shared__ __align__(16) ushort_t Bs[2][64 * 64];
  const int tid = threadIdx.x;
  const int lane = tid & 63, wave = tid >> 6;
  const int wr = wave >> 1, wc = wave & 1;
  const int l15 = lane & 15, lg = lane >> 4;
  const int sr8 = lane >> 3;
  const int skb = ((lane & 7) ^ sr8) << 4;
  const int sxor = (l15 & 7) << 4;
  f32x4 acc[2][2] = {};

  stage_tile64(A, Bm, As[0], Bs[0], bm, bn, K, 0, wave, sr8, skb);

  const int NT = K >> 6;
  for (int t = 0; t < NT; ++t) {
    const int cur = t & 1;
    if (t + 1 < NT) {
      stage_tile64(A, Bm, As[cur ^ 1], Bs[cur ^ 1], bm, bn, K, (t + 1) << 6,
                   wave, sr8, skb);
      asm volatile("s_waitcnt vmcnt(3)" ::: "memory");
    } else {
      asm volatile("s_waitcnt vmcnt(0)" ::: "memory");
    }
    __builtin_amdgcn_s_barrier();

    bf16x8 af[2][2], bfr[2][2];
#pragma unroll
    for (int kg = 0; kg < 2; ++kg) {
#pragma unroll
      for (int m = 0; m < 2; ++m) {
        int ra = wr * 32 + m * 16 + l15;
        af[kg][m] = *(const bf16x8*)((const char*)As[cur] + ra * 128 +
                                     ((kg * 64 + lg * 16) ^ sxor));
      }
#pragma unroll
      for (int n = 0; n < 2; ++n) {
        int rb = wc * 32 + n * 16 + l15;
        bfr[kg][n] = *(const bf16x8*)((const char*)Bs[cur] + rb * 128 +
                                      ((kg * 64 + lg * 16) ^ sxor));
      }
    }
    asm volatile("s_waitcnt lgkmcnt(0)" ::: "memory");
    __builtin_amdgcn_s_barrier();

    __builtin_amdgcn_s_setprio(1);
#pragma unroll
    for (int kg = 0; kg < 2; ++kg)
#pragma unroll
      for (int m = 0; m < 2; ++m)
#pragma unroll
        for (int n = 0; n < 2; ++n)
          acc[m][n] = __builtin_amdgcn_mfma_f32_16x16x32_bf16(
              af[kg][m], bfr[kg][n], acc[m][n], 0, 0, 0);
    __builtin_amdgcn_s_setprio(0);
  }

#pragma unroll
  for (int m = 0; m < 2; ++m)
#pragma unroll
    for (int n = 0; n < 2; ++n) {
      int row0 = bm + wr * 32 + m * 16 + lg * 4;
      int col = bn + wc * 32 + n * 16 + l15;
      float bb = bias[col];
#pragma unroll
      for (int j = 0; j < 4; ++j)
        Cf[(size_t)(row0 + j) * N + col] = acc[m][n][j] + bb;
    }
}

// ---- MFMA local attention (round-9, unchanged) ----
__global__ __launch_bounds__(256) void attn_mfma(
    const ushort_t* __restrict__ qkv, ushort_t* __restrict__ ctx) {
  const int b = blockIdx.z, h = blockIdx.y, tB = blockIdx.x * 128;
  __shared__ __align__(16) ushort_t KsPs[192 * 72];   // Ks | Ps | Ct aliased
  __shared__ __align__(16) ushort_t Vts[64][200];
  ushort_t (*Ks)[72] = (ushort_t(*)[72])KsPs;
  const int tid = threadIdx.x;
  const int wave = tid >> 6, lane = tid & 63;
  const int l15 = lane & 15, lg = lane >> 4;
  const size_t baseBT = (size_t)b * T_LEN;

  for (int idx = tid; idx < 1536; idx += 256) {
    int key = idx >> 3, d8 = (idx & 7) << 3;
    int t = tB - 32 + key;
    bf16x8 kv = {};
    if (t >= 0 && t < T_LEN)
      kv = *(const bf16x8*)(qkv + (baseBT + t) * 1536 + 512 + h * 64 + d8);
    *(bf16x8*)&Ks[key][d8] = kv;
  }
  for (int idx = tid; idx < 1536; idx += 256) {
    int d8 = (idx / 192) << 3, key = idx % 192;
    int t = tB - 32 + key;
    bf16x8 vv = {};
    if (t >= 0 && t < T_LEN)
      vv = *(const bf16x8*)(qkv + (baseBT + t) * 1536 + 1024 + h * 64 + d8);
#pragma unroll
    for (int j = 0; j < 8; ++j) Vts[d8 + j][key] = (ushort_t)vv[j];
  }
  bf16x8 qf[2][2];
#pragma unroll
  for (int m = 0; m < 2; ++m)
#pragma unroll
    for (int kg = 0; kg < 2; ++kg) {
      int tq = tB + wave * 32 + m * 16 + l15;
      qf[m][kg] = *(const bf16x8*)(qkv + (baseBT + tq) * 1536 + h * 64 + kg * 32 + lg * 8);
    }
  __syncthreads();

  f32x4 acc[2][6] = {};
#pragma unroll
  for (int n = 0; n < 6; ++n) {
    int keyr = wave * 32 + n * 16 + l15;
#pragma unroll
    for (int kg = 0; kg < 2; ++kg) {
      bf16x8 kf = *(const bf16x8*)&Ks[keyr][kg * 32 + lg * 8];
#pragma unroll
      for (int m = 0; m < 2; ++m)
        acc[m][n] = __builtin_amdgcn_mfma_f32_16x16x32_bf16(
            qf[m][kg], kf, acc[m][n], 0, 0, 0);
    }
  }
  __syncthreads();  // all waves' Ks reads done before Ps overwrites Ks

  ushort_t* Pw = KsPs + wave * 32 * 104;
#pragma unroll
  for (int m = 0; m < 2; ++m) {
#pragma unroll
    for (int jj = 0; jj < 4; ++jj) {
      int ql = m * 16 + lg * 4 + jj;
      float sv[6]; bool ok[6];
      float mx = -1e30f;
#pragma unroll
      for (int n = 0; n < 6; ++n) {
        int kl = n * 16 + l15;
        int tk = tB + wave * 32 - 32 + kl;
        int dd = kl - ql;
        ok[n] = (dd >= 0) && (dd <= 64) && (tk >= 0) && (tk < T_LEN);
        sv[n] = ok[n] ? acc[m][n][jj] * 0.125f : -1e30f;
        mx = fmaxf(mx, sv[n]);
      }
#pragma unroll
      for (int off = 8; off; off >>= 1) mx = fmaxf(mx, __shfl_xor(mx, off));
      float es[6], sum = 0.f;
#pragma unroll
      for (int n = 0; n < 6; ++n) { es[n] = ok[n] ? __expf(sv[n] - mx) : 0.f; sum += es[n]; }
#pragma unroll
      for (int off = 8; off; off >>= 1) sum += __shfl_xor(sum, off);
      float inv = 1.0f / sum;
#pragma unroll
      for (int n = 0; n < 6; ++n)
        Pw[ql * 104 + n * 16 + l15] = f2bf(es[n] * inv);
    }
  }
  __syncthreads();  // Ps writes visible to PV reads

  f32x4 acc2[2][4] = {};
#pragma unroll
  for (int ks = 0; ks < 3; ++ks) {
    bf16x8 pa[2], vb[4];
#pragma unroll
    for (int m = 0; m < 2; ++m)
      pa[m] = *(const bf16x8*)&Pw[(m * 16 + l15) * 104 + ks * 32 + lg * 8];
#pragma unroll
    for (int nn = 0; nn < 4; ++nn)
      vb[nn] = *(const bf16x8*)&Vts[nn * 16 + l15][wave * 32 + ks * 32 + lg * 8];
#pragma unroll
    for (int m = 0; m < 2; ++m)
#pragma unroll
      for (int nn = 0; nn < 4; ++nn)
        acc2[m][nn] = __builtin_amdgcn_mfma_f32_16x16x32_bf16(
            pa[m], vb[nn], acc2[m][nn], 0, 0, 0);
  }
  __syncthreads();  // Ps reads done before Ct overwrites the region

  ushort_t (*Ct)[72] = (ushort_t(*)[72])KsPs;
#pragma unroll
  for (int m = 0; m < 2; ++m)
#pragma unroll
    for (int nn = 0; nn < 4; ++nn)
#pragma unroll
      for (int jj = 0; jj < 4; ++jj)
        Ct[wave * 32 + m * 16 + lg * 4 + jj][nn * 16 + l15] = f2bf(acc2[m][nn][jj]);
  __syncthreads();

#pragma unroll
  for (int c = 0; c < 4; ++c) {
    int e = c * 256 + tid;
    int row = e >> 3, ch = (e & 7) << 3;
    *(bf16x8*)(ctx + (baseBT + tB + row) * 512 + h * 64 + ch) =
        *(const bf16x8*)&Ct[row][ch];
  }
}

// ---------------- launch ----------------
extern "C" void kernel_launch(void* const* d_in, const int* in_sizes, int n_in,
                              void* d_out, int out_size, void* d_ws, size_t ws_size,
                              hipStream_t stream) {
  const float* x = nullptr; const float* Wqkv = nullptr; const float* bqkv = nullptr;
  const float* Wout = nullptr; const float* bout = nullptr;
  for (int i = 0; i < n_in; ++i) {
    switch (in_sizes[i]) {
      case 4194304: x    = (const float*)d_in[i]; break;  // 4*2048*512
      case 786432:  Wqkv = (const float*)d_in[i]; break;  // 1536*512
      case 1536:    bqkv = (const float*)d_in[i]; break;
      case 262144:  Wout = (const float*)d_in[i]; break;  // 512*512
      case 512:     bout = (const float*)d_in[i]; break;
      default: break;
    }
  }
  const size_t need_ws =
      ((size_t)8192 * 1536 + (size_t)8192 * 512 +
       (size_t)1536 * 512 + (size_t)512 * 512) * 2;  // 34 MiB
  if (!x || !Wqkv || !bqkv || !Wout || !bout || ws_size < need_ws) return;
  float* out = (float*)d_out;

  ushort_t* qkvb = (ushort_t*)d_ws;                 // 24 MiB
  ushort_t* ctxb = qkvb + (size_t)8192 * 1536;      //  8 MiB
  ushort_t* w1b  = ctxb + (size_t)8192 * 512;       // 1.5 MiB
  ushort_t* w2b  = w1b + (size_t)1536 * 512;        // 0.5 MiB

  cvt_w<<<dim3(1024), dim3(256), 0, stream>>>(
      (const float4*)Wqkv, (const float4*)Wout,
      (ushort4*)w1b, (ushort4*)w2b);

  gemm1_fused<<<dim3(8, 64), dim3(512), 0, stream>>>(
      x, w1b, bqkv, qkvb, 1536, 512);

  attn_mfma<<<dim3(16, 8, 4), dim3(256), 0, stream>>>(qkvb, ctxb);

  gemm_db64<<<dim3(8, 64), dim3(512), 0, stream>>>(
      ctxb, w2b, bout, out, 512, 512);
}

// Round 16
// 67.205 us; speedup vs baseline: 1.0259x; 1.0259x over previous
//
#include <hip/hip_runtime.h>
#include <stdint.h>

#define T_LEN 2048

typedef unsigned short ushort_t;
typedef short bf16x8 __attribute__((ext_vector_type(8)));
typedef float f32x4  __attribute__((ext_vector_type(4)));

__device__ __forceinline__ unsigned short f2bf(float f) {
  union { float f; unsigned int u; } v; v.f = f;
  unsigned int u = v.u;
  return (unsigned short)((u + 0x7FFFu + ((u >> 16) & 1u)) >> 16);
}
__device__ __forceinline__ bf16x8 cvt8v(float4 a, float4 b) {
  bf16x8 r;
  r[0] = (short)f2bf(a.x); r[1] = (short)f2bf(a.y);
  r[2] = (short)f2bf(a.z); r[3] = (short)f2bf(a.w);
  r[4] = (short)f2bf(b.x); r[5] = (short)f2bf(b.y);
  r[6] = (short)f2bf(b.z); r[7] = (short)f2bf(b.w);
  return r;
}

// Panel-major XCD swizzle: all bx-blocks of one by-row land on one XCD.
__device__ __forceinline__ void xcd_swizzle_panel(int& bx, int& by) {
  int s = blockIdx.y * gridDim.x + blockIdx.x;
  int xcd = s & 7, idx = s >> 3;
  by = xcd + 8 * (idx / gridDim.x);
  bx = idx % gridDim.x;
}

// ---------------- convert fp32 -> bf16 (weights only) ----------------
__global__ __launch_bounds__(256) void cvt_w(
    const float4* __restrict__ w1, const float4* __restrict__ w2,
    ushort4* __restrict__ w1b, ushort4* __restrict__ w2b) {
  const int NW14 = (1536 * 512) / 4;
  const int NW24 = (512 * 512) / 4;
  int i = blockIdx.x * 256 + threadIdx.x;
  float4 v; ushort4* dst;
  if (i < NW14) { v = w1[i]; dst = w1b + i; }
  else { int j = i - NW14; if (j >= NW24) return; v = w2[j]; dst = w2b + j; }
  ushort4 o; o.x = f2bf(v.x); o.y = f2bf(v.y); o.z = f2bf(v.z); o.w = f2bf(v.w);
  *dst = o;
}

// ---- gemm1 (fused x-cvt, round-13 two-barrier skeleton + counted vmcnt) ----
// C_bf16 = x_f32[M][K] @ W_bf16[N][K]^T + bias. 128x192 tile, BK=64, 512 thr.
// Iter t: issue A(t+1)->regs + B(t+1) gload_lds; vmcnt(7) [retires B(t) only,
// this iter's 7 stay in flight]; barrier1; ds_read(t); lgkm0; barrier2;
// MFMA(t); sched_barrier; cvt+ds_write A(t+1) (write-late, vmcnt auto-wait
// covered by ds_read+MFMA); lgkm0. B(t+1) flies across barrier1 (true T4).
__global__ __launch_bounds__(512, 4) void gemm1_fused(
    const float* __restrict__ Af, const ushort_t* __restrict__ Bm,
    const float* __restrict__ bias, ushort_t* __restrict__ Cb, int N, int K) {
  int bx, by; xcd_swizzle_panel(bx, by);
  const int bm = by * 128, bn = bx * 192;
  __shared__ __align__(16) ushort_t As[2][128 * 64];
  __shared__ __align__(16) ushort_t Bs[2][192 * 64];
  const int tid = threadIdx.x;
  const int lane = tid & 63, wave = tid >> 6;
  const int wr = wave & 1, wc = wave >> 1;
  const int l15 = lane & 15, lg = lane >> 4;
  const int sr8 = lane >> 3;
  const int skb = ((lane & 7) ^ sr8) << 4;      // B source swizzle
  const int sxor = (l15 & 7) << 4;              // read-side XOR
  const int arow = tid >> 2, aseg = tid & 3, ar7 = arow & 7;
  const int au0 = ((aseg * 2) ^ ar7) << 4, au1 = ((aseg * 2 + 1) ^ ar7) << 4;
  const float* asrc = Af + (size_t)(bm + arow) * K + aseg * 16;
  f32x4 acc[4][3] = {};

#define STAGE_B(buf, kt_)                                          \
  _Pragma("unroll")                                                \
  for (int c = 0; c < 3; ++c) {                                    \
    int chunk = wave * 3 + c;                                      \
    int row = chunk * 8 + sr8;                                     \
    __builtin_amdgcn_global_load_lds(                              \
        (const __attribute__((address_space(1))) unsigned int*)    \
            ((const char*)(Bm + (size_t)(bn + row) * K + (kt_)) + skb), \
        (__attribute__((address_space(3))) unsigned int*)((buf) + chunk * 512), \
        16, 0, 0);                                                 \
  }

  // prologue: stage tile 0 completely, drain, barrier
  {
    const float4* ap = (const float4*)asrc;
    float4 p0 = ap[0], p1 = ap[1], p2 = ap[2], p3 = ap[3];
    STAGE_B(Bs[0], 0);
    char* dst = (char*)As[0] + arow * 128;
    *(bf16x8*)(dst + au0) = cvt8v(p0, p1);
    *(bf16x8*)(dst + au1) = cvt8v(p2, p3);
    asm volatile("s_waitcnt vmcnt(0) lgkmcnt(0)" ::: "memory");
    __builtin_amdgcn_s_barrier();
  }

  const int NT = K >> 6;
  for (int t = 0; t < NT; ++t) {
    const int cur = t & 1;
    float4 p0, p1, p2, p3;
    if (t + 1 < NT) {
      const float4* ap = (const float4*)(asrc + ((t + 1) << 6));
      p0 = ap[0]; p1 = ap[1]; p2 = ap[2]; p3 = ap[3];   // issue-early
      STAGE_B(Bs[cur ^ 1], (t + 1) << 6);
      // retire B(t)'s 3 gloads; the 7 just issued stay in flight.
      asm volatile("s_waitcnt vmcnt(7)" ::: "memory");
    } else {
      asm volatile("s_waitcnt vmcnt(0)" ::: "memory");
    }
    __builtin_amdgcn_s_barrier();   // barrier1: Bs[cur] + As[cur] visible

    bf16x8 af[2][4], bfr[2][3];
#pragma unroll
    for (int kg = 0; kg < 2; ++kg) {
#pragma unroll
      for (int m = 0; m < 4; ++m) {
        int ra = wr * 64 + m * 16 + l15;
        af[kg][m] = *(const bf16x8*)((const char*)As[cur] + ra * 128 +
                                     ((kg * 64 + lg * 16) ^ sxor));
      }
#pragma unroll
      for (int n = 0; n < 3; ++n) {
        int rb = wc * 48 + n * 16 + l15;
        bfr[kg][n] = *(const bf16x8*)((const char*)Bs[cur] + rb * 128 +
                                      ((kg * 64 + lg * 16) ^ sxor));
      }
    }
    asm volatile("s_waitcnt lgkmcnt(0)" ::: "memory");
    __builtin_amdgcn_s_barrier();   // barrier2: reads of cur done

    __builtin_amdgcn_s_setprio(1);
#pragma unroll
    for (int kg = 0; kg < 2; ++kg)
#pragma unroll
      for (int m = 0; m < 4; ++m)
#pragma unroll
        for (int n = 0; n < 3; ++n)
          acc[m][n] = __builtin_amdgcn_mfma_f32_16x16x32_bf16(
              af[kg][m], bfr[kg][n], acc[m][n], 0, 0, 0);
    __builtin_amdgcn_s_setprio(0);
    __builtin_amdgcn_sched_barrier(0);   // keep cvt/ds_write AFTER the MFMAs

    if (t + 1 < NT) {
      // write-late: A(t+1) loads had ds_read+MFMA (~500cy) of cover
      char* dst = (char*)As[cur ^ 1] + arow * 128;
      *(bf16x8*)(dst + au0) = cvt8v(p0, p1);
      *(bf16x8*)(dst + au1) = cvt8v(p2, p3);
      asm volatile("s_waitcnt lgkmcnt(0)" ::: "memory");  // visible pre-barrier1
    }
  }
#undef STAGE_B

  // C/D layout: col = lane&15, row = (lane>>4)*4 + j
#pragma unroll
  for (int m = 0; m < 4; ++m)
#pragma unroll
    for (int n = 0; n < 3; ++n) {
      int row0 = bm + wr * 64 + m * 16 + lg * 4;
      int col = bn + wc * 48 + n * 16 + l15;
      float bb = bias[col];
#pragma unroll
      for (int j = 0; j < 4; ++j)
        Cb[(size_t)(row0 + j) * N + col] = f2bf(acc[m][n][j] + bb);
    }
}

// ---- stage 128x64 A-tile + 64x64 B-tile, 8 waves (round-13, gemm2) ----
__device__ __forceinline__ void stage_tile64(
    const ushort_t* __restrict__ A, const ushort_t* __restrict__ Bm,
    ushort_t* As, ushort_t* Bs, int bm, int bn, int K, int kt,
    int wave, int sr8, int skb) {
#pragma unroll
  for (int c = 0; c < 2; ++c) {
    int chunk = wave * 2 + c;
    int row = chunk * 8 + sr8;
    __builtin_amdgcn_global_load_lds(
        (const __attribute__((address_space(1))) unsigned int*)
            ((const char*)(A + (size_t)(bm + row) * K + kt) + skb),
        (__attribute__((address_space(3))) unsigned int*)(As + chunk * 512),
        16, 0, 0);
  }
  {
    int row = wave * 8 + sr8;
    __builtin_amdgcn_global_load_lds(
        (const __attribute__((address_space(1))) unsigned int*)
            ((const char*)(Bm + (size_t)(bn + row) * K + kt) + skb),
        (__attribute__((address_space(3))) unsigned int*)(Bs + wave * 512),
        16, 0, 0);
  }
}

// ---- gemm2: 128x64 tile (round-13 proven, unchanged) ----
__global__ __launch_bounds__(512, 4) void gemm_db64(
    const ushort_t* __restrict__ A, const ushort_t* __restrict__ Bm,
    const float* __restrict__ bias, float* __restrict__ Cf, int N, int K) {
  int bx, by; xcd_swizzle_panel(bx, by);
  const int bm = by * 128, bn = bx * 64;
  __shared__ __align__(16) ushort_t As[2][128 * 64];
  __shared__ __align__(16) ushort_t Bs[2][64 * 64];
  const int tid = threadIdx.x;
  const int lane = tid & 63, wave = tid >> 6;
  const int wr = wave >> 1, wc = wave & 1;
  const int l15 = lane & 15, lg = lane >> 4;
  const int sr8 = lane >> 3;
  const int skb = ((lane & 7) ^ sr8) << 4;
  const int sxor = (l15 & 7) << 4;
  f32x4 acc[2][2] = {};

  stage_tile64(A, Bm, As[0], Bs[0], bm, bn, K, 0, wave, sr8, skb);

  const int NT = K >> 6;
  for (int t = 0; t < NT; ++t) {
    const int cur = t & 1;
    if (t + 1 < NT) {
      stage_tile64(A, Bm, As[cur ^ 1], Bs[cur ^ 1], bm, bn, K, (t + 1) << 6,
                   wave, sr8, skb);
      asm volatile("s_waitcnt vmcnt(3)" ::: "memory");
    } else {
      asm volatile("s_waitcnt vmcnt(0)" ::: "memory");
    }
    __builtin_amdgcn_s_barrier();

    bf16x8 af[2][2], bfr[2][2];
#pragma unroll
    for (int kg = 0; kg < 2; ++kg) {
#pragma unroll
      for (int m = 0; m < 2; ++m) {
        int ra = wr * 32 + m * 16 + l15;
        af[kg][m] = *(const bf16x8*)((const char*)As[cur] + ra * 128 +
                                     ((kg * 64 + lg * 16) ^ sxor));
      }
#pragma unroll
      for (int n = 0; n < 2; ++n) {
        int rb = wc * 32 + n * 16 + l15;
        bfr[kg][n] = *(const bf16x8*)((const char*)Bs[cur] + rb * 128 +
                                      ((kg * 64 + lg * 16) ^ sxor));
      }
    }
    asm volatile("s_waitcnt lgkmcnt(0)" ::: "memory");
    __builtin_amdgcn_s_barrier();

    __builtin_amdgcn_s_setprio(1);
#pragma unroll
    for (int kg = 0; kg < 2; ++kg)
#pragma unroll
      for (int m = 0; m < 2; ++m)
#pragma unroll
        for (int n = 0; n < 2; ++n)
          acc[m][n] = __builtin_amdgcn_mfma_f32_16x16x32_bf16(
              af[kg][m], bfr[kg][n], acc[m][n], 0, 0, 0);
    __builtin_amdgcn_s_setprio(0);
  }

#pragma unroll
  for (int m = 0; m < 2; ++m)
#pragma unroll
    for (int n = 0; n < 2; ++n) {
      int row0 = bm + wr * 32 + m * 16 + lg * 4;
      int col = bn + wc * 32 + n * 16 + l15;
      float bb = bias[col];
#pragma unroll
      for (int j = 0; j < 4; ++j)
        Cf[(size_t)(row0 + j) * N + col] = acc[m][n][j] + bb;
    }
}

// ---- MFMA local attention (round-9, unchanged) ----
__global__ __launch_bounds__(256) void attn_mfma(
    const ushort_t* __restrict__ qkv, ushort_t* __restrict__ ctx) {
  const int b = blockIdx.z, h = blockIdx.y, tB = blockIdx.x * 128;
  __shared__ __align__(16) ushort_t KsPs[192 * 72];   // Ks | Ps | Ct aliased
  __shared__ __align__(16) ushort_t Vts[64][200];
  ushort_t (*Ks)[72] = (ushort_t(*)[72])KsPs;
  const int tid = threadIdx.x;
  const int wave = tid >> 6, lane = tid & 63;
  const int l15 = lane & 15, lg = lane >> 4;
  const size_t baseBT = (size_t)b * T_LEN;

  for (int idx = tid; idx < 1536; idx += 256) {
    int key = idx >> 3, d8 = (idx & 7) << 3;
    int t = tB - 32 + key;
    bf16x8 kv = {};
    if (t >= 0 && t < T_LEN)
      kv = *(const bf16x8*)(qkv + (baseBT + t) * 1536 + 512 + h * 64 + d8);
    *(bf16x8*)&Ks[key][d8] = kv;
  }
  for (int idx = tid; idx < 1536; idx += 256) {
    int d8 = (idx / 192) << 3, key = idx % 192;
    int t = tB - 32 + key;
    bf16x8 vv = {};
    if (t >= 0 && t < T_LEN)
      vv = *(const bf16x8*)(qkv + (baseBT + t) * 1536 + 1024 + h * 64 + d8);
#pragma unroll
    for (int j = 0; j < 8; ++j) Vts[d8 + j][key] = (ushort_t)vv[j];
  }
  bf16x8 qf[2][2];
#pragma unroll
  for (int m = 0; m < 2; ++m)
#pragma unroll
    for (int kg = 0; kg < 2; ++kg) {
      int tq = tB + wave * 32 + m * 16 + l15;
      qf[m][kg] = *(const bf16x8*)(qkv + (baseBT + tq) * 1536 + h * 64 + kg * 32 + lg * 8);
    }
  __syncthreads();

  f32x4 acc[2][6] = {};
#pragma unroll
  for (int n = 0; n < 6; ++n) {
    int keyr = wave * 32 + n * 16 + l15;
#pragma unroll
    for (int kg = 0; kg < 2; ++kg) {
      bf16x8 kf = *(const bf16x8*)&Ks[keyr][kg * 32 + lg * 8];
#pragma unroll
      for (int m = 0; m < 2; ++m)
        acc[m][n] = __builtin_amdgcn_mfma_f32_16x16x32_bf16(
            qf[m][kg], kf, acc[m][n], 0, 0, 0);
    }
  }
  __syncthreads();  // all waves' Ks reads done before Ps overwrites Ks

  ushort_t* Pw = KsPs + wave * 32 * 104;
#pragma unroll
  for (int m = 0; m < 2; ++m) {
#pragma unroll
    for (int jj = 0; jj < 4; ++jj) {
      int ql = m * 16 + lg * 4 + jj;
      float sv[6]; bool ok[6];
      float mx = -1e30f;
#pragma unroll
      for (int n = 0; n < 6; ++n) {
        int kl = n * 16 + l15;
        int tk = tB + wave * 32 - 32 + kl;
        int dd = kl - ql;
        ok[n] = (dd >= 0) && (dd <= 64) && (tk >= 0) && (tk < T_LEN);
        sv[n] = ok[n] ? acc[m][n][jj] * 0.125f : -1e30f;
        mx = fmaxf(mx, sv[n]);
      }
#pragma unroll
      for (int off = 8; off; off >>= 1) mx = fmaxf(mx, __shfl_xor(mx, off));
      float es[6], sum = 0.f;
#pragma unroll
      for (int n = 0; n < 6; ++n) { es[n] = ok[n] ? __expf(sv[n] - mx) : 0.f; sum += es[n]; }
#pragma unroll
      for (int off = 8; off; off >>= 1) sum += __shfl_xor(sum, off);
      float inv = 1.0f / sum;
#pragma unroll
      for (int n = 0; n < 6; ++n)
        Pw[ql * 104 + n * 16 + l15] = f2bf(es[n] * inv);
    }
  }
  __syncthreads();  // Ps writes visible to PV reads

  f32x4 acc2[2][4] = {};
#pragma unroll
  for (int ks = 0; ks < 3; ++ks) {
    bf16x8 pa[2], vb[4];
#pragma unroll
    for (int m = 0; m < 2; ++m)
      pa[m] = *(const bf16x8*)&Pw[(m * 16 + l15) * 104 + ks * 32 + lg * 8];
#pragma unroll
    for (int nn = 0; nn < 4; ++nn)
      vb[nn] = *(const bf16x8*)&Vts[nn * 16 + l15][wave * 32 + ks * 32 + lg * 8];
#pragma unroll
    for (int m = 0; m < 2; ++m)
#pragma unroll
      for (int nn = 0; nn < 4; ++nn)
        acc2[m][nn] = __builtin_amdgcn_mfma_f32_16x16x32_bf16(
            pa[m], vb[nn], acc2[m][nn], 0, 0, 0);
  }
  __syncthreads();  // Ps reads done before Ct overwrites the region

  ushort_t (*Ct)[72] = (ushort_t(*)[72])KsPs;
#pragma unroll
  for (int m = 0; m < 2; ++m)
#pragma unroll
    for (int nn = 0; nn < 4; ++nn)
#pragma unroll
      for (int jj = 0; jj < 4; ++jj)
        Ct[wave * 32 + m * 16 + lg * 4 + jj][nn * 16 + l15] = f2bf(acc2[m][nn][jj]);
  __syncthreads();

#pragma unroll
  for (int c = 0; c < 4; ++c) {
    int e = c * 256 + tid;
    int row = e >> 3, ch = (e & 7) << 3;
    *(bf16x8*)(ctx + (baseBT + tB + row) * 512 + h * 64 + ch) =
        *(const bf16x8*)&Ct[row][ch];
  }
}

// ---------------- launch ----------------
extern "C" void kernel_launch(void* const* d_in, const int* in_sizes, int n_in,
                              void* d_out, int out_size, void* d_ws, size_t ws_size,
                              hipStream_t stream) {
  const float* x = nullptr; const float* Wqkv = nullptr; const float* bqkv = nullptr;
  const float* Wout = nullptr; const float* bout = nullptr;
  for (int i = 0; i < n_in; ++i) {
    switch (in_sizes[i]) {
      case 4194304: x    = (const float*)d_in[i]; break;  // 4*2048*512
      case 786432:  Wqkv = (const float*)d_in[i]; break;  // 1536*512
      case 1536:    bqkv = (const float*)d_in[i]; break;
      case 262144:  Wout = (const float*)d_in[i]; break;  // 512*512
      case 512:     bout = (const float*)d_in[i]; break;
      default: break;
    }
  }
  const size_t need_ws =
      ((size_t)8192 * 1536 + (size_t)8192 * 512 +
       (size_t)1536 * 512 + (size_t)512 * 512) * 2;  // 34 MiB
  if (!x || !Wqkv || !bqkv || !Wout || !bout || ws_size < need_ws) return;
  float* out = (float*)d_out;

  ushort_t* qkvb = (ushort_t*)d_ws;                 // 24 MiB
  ushort_t* ctxb = qkvb + (size_t)8192 * 1536;      //  8 MiB
  ushort_t* w1b  = ctxb + (size_t)8192 * 512;       // 1.5 MiB
  ushort_t* w2b  = w1b + (size_t)1536 * 512;        // 0.5 MiB

  cvt_w<<<dim3(1024), dim3(256), 0, stream>>>(
      (const float4*)Wqkv, (const float4*)Wout,
      (ushort4*)w1b, (ushort4*)w2b);

  gemm1_fused<<<dim3(8, 64), dim3(512), 0, stream>>>(
      x, w1b, bqkv, qkvb, 1536, 512);

  attn_mfma<<<dim3(16, 8, 4), dim3(256), 0, stream>>>(qkvb, ctxb);

  gemm_db64<<<dim3(8, 64), dim3(512), 0, stream>>>(
      ctxb, w2b, bout, out, 512, 512);
}

// Round 17
// 52.971 us; speedup vs baseline: 1.3016x; 1.2687x over previous
//
#include <hip/hip_runtime.h>
#include <stdint.h>

#define T_LEN 2048

typedef unsigned short ushort_t;
typedef short bf16x8 __attribute__((ext_vector_type(8)));
typedef float f32x4  __attribute__((ext_vector_type(4)));

__device__ __forceinline__ unsigned short f2bf(float f) {
  union { float f; unsigned int u; } v; v.f = f;
  unsigned int u = v.u;
  return (unsigned short)((u + 0x7FFFu + ((u >> 16) & 1u)) >> 16);
}

// Panel-major XCD swizzle: all bx-blocks of one by-row land on one XCD
// (A-panel stays in that XCD's L2). Needs gridDim.y % 8 == 0 (64 here).
__device__ __forceinline__ void xcd_swizzle_panel(int& bx, int& by) {
  int s = blockIdx.y * gridDim.x + blockIdx.x;
  int xcd = s & 7, idx = s >> 3;
  by = xcd + 8 * (idx / gridDim.x);
  bx = idx % gridDim.x;
}

// ---------------- convert fp32 -> bf16 (x, Wqkv, Wout) ----------------
__global__ __launch_bounds__(256) void cvt_kernel(
    const float4* __restrict__ x, const float4* __restrict__ w1, const float4* __restrict__ w2,
    ushort4* __restrict__ xb, ushort4* __restrict__ w1b, ushort4* __restrict__ w2b) {
  const int NX4 = (8192 * 512) / 4;
  const int NW14 = (1536 * 512) / 4;
  const int NW24 = (512 * 512) / 4;
  int i = blockIdx.x * 256 + threadIdx.x;
  float4 v; ushort4* dst;
  if (i < NX4) { v = x[i]; dst = xb + i; }
  else if (i < NX4 + NW14) { int j = i - NX4; v = w1[j]; dst = w1b + j; }
  else { int j = i - NX4 - NW14; if (j >= NW24) return; v = w2[j]; dst = w2b + j; }
  ushort4 o; o.x = f2bf(v.x); o.y = f2bf(v.y); o.z = f2bf(v.z); o.w = f2bf(v.w);
  *dst = o;
}

// ---- stage 128x64 A-tile + 192x64 B-tile via global_load_lds, 8 waves ----
__device__ __forceinline__ void stage_192(
    const ushort_t* __restrict__ A, const ushort_t* __restrict__ Bm,
    ushort_t* As, ushort_t* Bs, int bm, int bn, int K, int kt,
    int wave, int sr8, int skb) {
#pragma unroll
  for (int c = 0; c < 2; ++c) {
    int chunk = wave * 2 + c;           // 0..15
    int row = chunk * 8 + sr8;          // 0..127
    __builtin_amdgcn_global_load_lds(
        (const __attribute__((address_space(1))) unsigned int*)
            ((const char*)(A + (size_t)(bm + row) * K + kt) + skb),
        (__attribute__((address_space(3))) unsigned int*)(As + chunk * 512),
        16, 0, 0);
  }
#pragma unroll
  for (int c = 0; c < 3; ++c) {
    int chunk = wave * 3 + c;           // 0..23
    int row = chunk * 8 + sr8;          // 0..191
    __builtin_amdgcn_global_load_lds(
        (const __attribute__((address_space(1))) unsigned int*)
            ((const char*)(Bm + (size_t)(bn + row) * K + kt) + skb),
        (__attribute__((address_space(3))) unsigned int*)(Bs + chunk * 512),
        16, 0, 0);
  }
}

// ---- gemm1: 128x192 tile, BK=64, 512 threads, counted vmcnt(5) dbuf ----
// (round-12/13 proven)
__global__ __launch_bounds__(512, 4) void gemm_db192(
    const ushort_t* __restrict__ A, const ushort_t* __restrict__ Bm,
    const float* __restrict__ bias, ushort_t* __restrict__ Cb, int N, int K) {
  int bx, by; xcd_swizzle_panel(bx, by);
  const int bm = by * 128, bn = bx * 192;
  __shared__ __align__(16) ushort_t As[2][128 * 64];
  __shared__ __align__(16) ushort_t Bs[2][192 * 64];
  const int tid = threadIdx.x;
  const int lane = tid & 63, wave = tid >> 6;
  const int wr = wave & 1, wc = wave >> 1;      // 2 row-strips x 4 col-strips
  const int l15 = lane & 15, lg = lane >> 4;
  const int sr8 = lane >> 3;
  const int skb = ((lane & 7) ^ sr8) << 4;
  const int sxor = (l15 & 7) << 4;
  f32x4 acc[4][3] = {};

  stage_192(A, Bm, As[0], Bs[0], bm, bn, K, 0, wave, sr8, skb);

  const int NT = K >> 6;
  for (int t = 0; t < NT; ++t) {
    const int cur = t & 1;
    if (t + 1 < NT) {
      stage_192(A, Bm, As[cur ^ 1], Bs[cur ^ 1], bm, bn, K, (t + 1) << 6,
                wave, sr8, skb);
      asm volatile("s_waitcnt vmcnt(5)" ::: "memory");
    } else {
      asm volatile("s_waitcnt vmcnt(0)" ::: "memory");
    }
    __builtin_amdgcn_s_barrier();

    bf16x8 af[2][4], bfr[2][3];
#pragma unroll
    for (int kg = 0; kg < 2; ++kg) {
#pragma unroll
      for (int m = 0; m < 4; ++m) {
        int ra = wr * 64 + m * 16 + l15;
        af[kg][m] = *(const bf16x8*)((const char*)As[cur] + ra * 128 +
                                     ((kg * 64 + lg * 16) ^ sxor));
      }
#pragma unroll
      for (int n = 0; n < 3; ++n) {
        int rb = wc * 48 + n * 16 + l15;
        bfr[kg][n] = *(const bf16x8*)((const char*)Bs[cur] + rb * 128 +
                                      ((kg * 64 + lg * 16) ^ sxor));
      }
    }
    asm volatile("s_waitcnt lgkmcnt(0)" ::: "memory");
    __builtin_amdgcn_s_barrier();

    __builtin_amdgcn_s_setprio(1);
#pragma unroll
    for (int kg = 0; kg < 2; ++kg)
#pragma unroll
      for (int m = 0; m < 4; ++m)
#pragma unroll
        for (int n = 0; n < 3; ++n)
          acc[m][n] = __builtin_amdgcn_mfma_f32_16x16x32_bf16(
              af[kg][m], bfr[kg][n], acc[m][n], 0, 0, 0);
    __builtin_amdgcn_s_setprio(0);
  }

  // C/D layout: col = lane&15, row = (lane>>4)*4 + j
#pragma unroll
  for (int m = 0; m < 4; ++m)
#pragma unroll
    for (int n = 0; n < 3; ++n) {
      int row0 = bm + wr * 64 + m * 16 + lg * 4;
      int col = bn + wc * 48 + n * 16 + l15;
      float bb = bias[col];
#pragma unroll
      for (int j = 0; j < 4; ++j)
        Cb[(size_t)(row0 + j) * N + col] = f2bf(acc[m][n][j] + bb);
    }
}

// ---- stage 128x64 A-tile + 64x64 B-tile, 8 waves (3 loads/wave) ----
__device__ __forceinline__ void stage_tile64(
    const ushort_t* __restrict__ A, const ushort_t* __restrict__ Bm,
    ushort_t* As, ushort_t* Bs, int bm, int bn, int K, int kt,
    int wave, int sr8, int skb) {
#pragma unroll
  for (int c = 0; c < 2; ++c) {
    int chunk = wave * 2 + c;
    int row = chunk * 8 + sr8;
    __builtin_amdgcn_global_load_lds(
        (const __attribute__((address_space(1))) unsigned int*)
            ((const char*)(A + (size_t)(bm + row) * K + kt) + skb),
        (__attribute__((address_space(3))) unsigned int*)(As + chunk * 512),
        16, 0, 0);
  }
  {
    int row = wave * 8 + sr8;
    __builtin_amdgcn_global_load_lds(
        (const __attribute__((address_space(1))) unsigned int*)
            ((const char*)(Bm + (size_t)(bn + row) * K + kt) + skb),
        (__attribute__((address_space(3))) unsigned int*)(Bs + wave * 512),
        16, 0, 0);
  }
}

// ---- gemm2: 128x64 tile (round-13 proven, unchanged) ----
__global__ __launch_bounds__(512, 4) void gemm_db64(
    const ushort_t* __restrict__ A, const ushort_t* __restrict__ Bm,
    const float* __restrict__ bias, float* __restrict__ Cf, int N, int K) {
  int bx, by; xcd_swizzle_panel(bx, by);
  const int bm = by * 128, bn = bx * 64;
  __shared__ __align__(16) ushort_t As[2][128 * 64];
  __shared__ __align__(16) ushort_t Bs[2][64 * 64];
  const int tid = threadIdx.x;
  const int lane = tid & 63, wave = tid >> 6;
  const int wr = wave >> 1, wc = wave & 1;
  const int l15 = lane & 15, lg = lane >> 4;
  const int sr8 = lane >> 3;
  const int skb = ((lane & 7) ^ sr8) << 4;
  const int sxor = (l15 & 7) << 4;
  f32x4 acc[2][2] = {};

  stage_tile64(A, Bm, As[0], Bs[0], bm, bn, K, 0, wave, sr8, skb);

  const int NT = K >> 6;
  for (int t = 0; t < NT; ++t) {
    const int cur = t & 1;
    if (t + 1 < NT) {
      stage_tile64(A, Bm, As[cur ^ 1], Bs[cur ^ 1], bm, bn, K, (t + 1) << 6,
                   wave, sr8, skb);
      asm volatile("s_waitcnt vmcnt(3)" ::: "memory");
    } else {
      asm volatile("s_waitcnt vmcnt(0)" ::: "memory");
    }
    __builtin_amdgcn_s_barrier();

    bf16x8 af[2][2], bfr[2][2];
#pragma unroll
    for (int kg = 0; kg < 2; ++kg) {
#pragma unroll
      for (int m = 0; m < 2; ++m) {
        int ra = wr * 32 + m * 16 + l15;
        af[kg][m] = *(const bf16x8*)((const char*)As[cur] + ra * 128 +
                                     ((kg * 64 + lg * 16) ^ sxor));
      }
#pragma unroll
      for (int n = 0; n < 2; ++n) {
        int rb = wc * 32 + n * 16 + l15;
        bfr[kg][n] = *(const bf16x8*)((const char*)Bs[cur] + rb * 128 +
                                      ((kg * 64 + lg * 16) ^ sxor));
      }
    }
    asm volatile("s_waitcnt lgkmcnt(0)" ::: "memory");
    __builtin_amdgcn_s_barrier();

    __builtin_amdgcn_s_setprio(1);
#pragma unroll
    for (int kg = 0; kg < 2; ++kg)
#pragma unroll
      for (int m = 0; m < 2; ++m)
#pragma unroll
        for (int n = 0; n < 2; ++n)
          acc[m][n] = __builtin_amdgcn_mfma_f32_16x16x32_bf16(
              af[kg][m], bfr[kg][n], acc[m][n], 0, 0, 0);
    __builtin_amdgcn_s_setprio(0);
  }

#pragma unroll
  for (int m = 0; m < 2; ++m)
#pragma unroll
    for (int n = 0; n < 2; ++n) {
      int row0 = bm + wr * 32 + m * 16 + lg * 4;
      int col = bn + wc * 32 + n * 16 + l15;
      float bb = bias[col];
#pragma unroll
      for (int j = 0; j < 4; ++j)
        Cf[(size_t)(row0 + j) * N + col] = acc[m][n][j] + bb;
    }
}

// ---- MFMA local attention (round-9, unchanged) ----
__global__ __launch_bounds__(256) void attn_mfma(
    const ushort_t* __restrict__ qkv, ushort_t* __restrict__ ctx) {
  const int b = blockIdx.z, h = blockIdx.y, tB = blockIdx.x * 128;
  __shared__ __align__(16) ushort_t KsPs[192 * 72];   // Ks | Ps | Ct aliased
  __shared__ __align__(16) ushort_t Vts[64][200];
  ushort_t (*Ks)[72] = (ushort_t(*)[72])KsPs;
  const int tid = threadIdx.x;
  const int wave = tid >> 6, lane = tid & 63;
  const int l15 = lane & 15, lg = lane >> 4;
  const size_t baseBT = (size_t)b * T_LEN;

  for (int idx = tid; idx < 1536; idx += 256) {
    int key = idx >> 3, d8 = (idx & 7) << 3;
    int t = tB - 32 + key;
    bf16x8 kv = {};
    if (t >= 0 && t < T_LEN)
      kv = *(const bf16x8*)(qkv + (baseBT + t) * 1536 + 512 + h * 64 + d8);
    *(bf16x8*)&Ks[key][d8] = kv;
  }
  for (int idx = tid; idx < 1536; idx += 256) {
    int d8 = (idx / 192) << 3, key = idx % 192;
    int t = tB - 32 + key;
    bf16x8 vv = {};
    if (t >= 0 && t < T_LEN)
      vv = *(const bf16x8*)(qkv + (baseBT + t) * 1536 + 1024 + h * 64 + d8);
#pragma unroll
    for (int j = 0; j < 8; ++j) Vts[d8 + j][key] = (ushort_t)vv[j];
  }
  bf16x8 qf[2][2];
#pragma unroll
  for (int m = 0; m < 2; ++m)
#pragma unroll
    for (int kg = 0; kg < 2; ++kg) {
      int tq = tB + wave * 32 + m * 16 + l15;
      qf[m][kg] = *(const bf16x8*)(qkv + (baseBT + tq) * 1536 + h * 64 + kg * 32 + lg * 8);
    }
  __syncthreads();

  f32x4 acc[2][6] = {};
#pragma unroll
  for (int n = 0; n < 6; ++n) {
    int keyr = wave * 32 + n * 16 + l15;
#pragma unroll
    for (int kg = 0; kg < 2; ++kg) {
      bf16x8 kf = *(const bf16x8*)&Ks[keyr][kg * 32 + lg * 8];
#pragma unroll
      for (int m = 0; m < 2; ++m)
        acc[m][n] = __builtin_amdgcn_mfma_f32_16x16x32_bf16(
            qf[m][kg], kf, acc[m][n], 0, 0, 0);
    }
  }
  __syncthreads();  // all waves' Ks reads done before Ps overwrites Ks

  ushort_t* Pw = KsPs + wave * 32 * 104;
#pragma unroll
  for (int m = 0; m < 2; ++m) {
#pragma unroll
    for (int jj = 0; jj < 4; ++jj) {
      int ql = m * 16 + lg * 4 + jj;
      float sv[6]; bool ok[6];
      float mx = -1e30f;
#pragma unroll
      for (int n = 0; n < 6; ++n) {
        int kl = n * 16 + l15;
        int tk = tB + wave * 32 - 32 + kl;
        int dd = kl - ql;
        ok[n] = (dd >= 0) && (dd <= 64) && (tk >= 0) && (tk < T_LEN);
        sv[n] = ok[n] ? acc[m][n][jj] * 0.125f : -1e30f;
        mx = fmaxf(mx, sv[n]);
      }
#pragma unroll
      for (int off = 8; off; off >>= 1) mx = fmaxf(mx, __shfl_xor(mx, off));
      float es[6], sum = 0.f;
#pragma unroll
      for (int n = 0; n < 6; ++n) { es[n] = ok[n] ? __expf(sv[n] - mx) : 0.f; sum += es[n]; }
#pragma unroll
      for (int off = 8; off; off >>= 1) sum += __shfl_xor(sum, off);
      float inv = 1.0f / sum;
#pragma unroll
      for (int n = 0; n < 6; ++n)
        Pw[ql * 104 + n * 16 + l15] = f2bf(es[n] * inv);
    }
  }
  __syncthreads();  // Ps writes visible to PV reads

  f32x4 acc2[2][4] = {};
#pragma unroll
  for (int ks = 0; ks < 3; ++ks) {
    bf16x8 pa[2], vb[4];
#pragma unroll
    for (int m = 0; m < 2; ++m)
      pa[m] = *(const bf16x8*)&Pw[(m * 16 + l15) * 104 + ks * 32 + lg * 8];
#pragma unroll
    for (int nn = 0; nn < 4; ++nn)
      vb[nn] = *(const bf16x8*)&Vts[nn * 16 + l15][wave * 32 + ks * 32 + lg * 8];
#pragma unroll
    for (int m = 0; m < 2; ++m)
#pragma unroll
      for (int nn = 0; nn < 4; ++nn)
        acc2[m][nn] = __builtin_amdgcn_mfma_f32_16x16x32_bf16(
            pa[m], vb[nn], acc2[m][nn], 0, 0, 0);
  }
  __syncthreads();  // Ps reads done before Ct overwrites the region

  ushort_t (*Ct)[72] = (ushort_t(*)[72])KsPs;
#pragma unroll
  for (int m = 0; m < 2; ++m)
#pragma unroll
    for (int nn = 0; nn < 4; ++nn)
#pragma unroll
      for (int jj = 0; jj < 4; ++jj)
        Ct[wave * 32 + m * 16 + lg * 4 + jj][nn * 16 + l15] = f2bf(acc2[m][nn][jj]);
  __syncthreads();

#pragma unroll
  for (int c = 0; c < 4; ++c) {
    int e = c * 256 + tid;
    int row = e >> 3, ch = (e & 7) << 3;
    *(bf16x8*)(ctx + (baseBT + tB + row) * 512 + h * 64 + ch) =
        *(const bf16x8*)&Ct[row][ch];
  }
}

// ---------------- launch ----------------
extern "C" void kernel_launch(void* const* d_in, const int* in_sizes, int n_in,
                              void* d_out, int out_size, void* d_ws, size_t ws_size,
                              hipStream_t stream) {
  const float* x = nullptr; const float* Wqkv = nullptr; const float* bqkv = nullptr;
  const float* Wout = nullptr; const float* bout = nullptr;
  for (int i = 0; i < n_in; ++i) {
    switch (in_sizes[i]) {
      case 4194304: x    = (const float*)d_in[i]; break;  // 4*2048*512
      case 786432:  Wqkv = (const float*)d_in[i]; break;  // 1536*512
      case 1536:    bqkv = (const float*)d_in[i]; break;
      case 262144:  Wout = (const float*)d_in[i]; break;  // 512*512
      case 512:     bout = (const float*)d_in[i]; break;
      default: break;
    }
  }
  const size_t need_ws =
      ((size_t)8192 * 1536 + (size_t)8192 * 512 * 2 +
       (size_t)1536 * 512 + (size_t)512 * 512) * 2;  // 42 MiB
  if (!x || !Wqkv || !bqkv || !Wout || !bout || ws_size < need_ws) return;
  float* out = (float*)d_out;

  ushort_t* qkvb = (ushort_t*)d_ws;                 // 24 MiB
  ushort_t* ctxb = qkvb + (size_t)8192 * 1536;      //  8 MiB
  ushort_t* xb   = ctxb + (size_t)8192 * 512;       //  8 MiB
  ushort_t* w1b  = xb + (size_t)8192 * 512;         // 1.5 MiB
  ushort_t* w2b  = w1b + (size_t)1536 * 512;        // 0.5 MiB

  cvt_kernel<<<dim3(5120), dim3(256), 0, stream>>>(
      (const float4*)x, (const float4*)Wqkv, (const float4*)Wout,
      (ushort4*)xb, (ushort4*)w1b, (ushort4*)w2b);

  gemm_db192<<<dim3(8, 64), dim3(512), 0, stream>>>(
      xb, w1b, bqkv, qkvb, 1536, 512);

  attn_mfma<<<dim3(16, 8, 4), dim3(256), 0, stream>>>(qkvb, ctxb);

  gemm_db64<<<dim3(8, 64), dim3(512), 0, stream>>>(
      ctxb, w2b, bout, out, 512, 512);
}